// Round 4
// baseline (328.346 us; speedup 1.0000x reference)
//
#include <hip/hip_runtime.h>
#include <stdint.h>

// ---------- types ----------
typedef __bf16 bf16x8 __attribute__((ext_vector_type(8)));
typedef float f32x4 __attribute__((ext_vector_type(4)));
typedef unsigned short us4_t __attribute__((ext_vector_type(4)));
typedef unsigned short us8_t __attribute__((ext_vector_type(8)));

#define LDSK 40  // padded row (reg-staged tiles): 32 bf16 + 8 pad

__device__ __forceinline__ unsigned short f2bf(float f) {
  __bf16 b = (__bf16)f;
  return __builtin_bit_cast(unsigned short, b);
}
__device__ __forceinline__ float bf2f(unsigned short u) {
  union { uint32_t u; float f; } v; v.u = ((uint32_t)u) << 16;
  return v.f;
}

// async global->LDS, 16B per lane (wave-uniform LDS base + lane*16)
__device__ __forceinline__ void gload16(const unsigned short* g, unsigned short* l) {
  __builtin_amdgcn_global_load_lds(
      (const __attribute__((address_space(1))) void*)g,
      (__attribute__((address_space(3))) void*)l, 16, 0, 0);
}

// Stage a 128x32-short tile (linear [128][32] LDS) via 8 x global_load_lds.
__device__ __forceinline__ void stage_tile(const unsigned short* g, size_t ldg,
                                           unsigned short* lds, int wid, int lane) {
#pragma unroll
  for (int i = 0; i < 2; ++i) {
    int seg = wid * 2 + i;  // 0..7, 16 rows each
    const unsigned short* gp = g + (size_t)(seg * 16 + (lane >> 2)) * ldg + (lane & 3) * 8;
    gload16(gp, lds + seg * 512);
  }
}

// =====================================================================
// Convert x (16.7M f32) and W (0.52M f32) to bf16 (into out region).
// =====================================================================
__global__ __launch_bounds__(256) void k_convert(
    const float* __restrict__ X, const float* __restrict__ W,
    unsigned short* __restrict__ Xb, unsigned short* __restrict__ Wb) {
  const size_t idx = (size_t)blockIdx.x * 256 + threadIdx.x;
  const size_t stride = (size_t)gridDim.x * 256;
  for (size_t i = idx; i < (size_t)16777216 / 8; i += stride) {
    float4 f0 = ((const float4*)X)[2 * i], f1 = ((const float4*)X)[2 * i + 1];
    us8_t w = { f2bf(f0.x), f2bf(f0.y), f2bf(f0.z), f2bf(f0.w),
                f2bf(f1.x), f2bf(f1.y), f2bf(f1.z), f2bf(f1.w) };
    ((us8_t*)Xb)[i] = w;
  }
  for (size_t i = idx; i < (size_t)524288 / 8; i += stride) {
    float4 f0 = ((const float4*)W)[2 * i], f1 = ((const float4*)W)[2 * i + 1];
    us8_t w = { f2bf(f0.x), f2bf(f0.y), f2bf(f0.z), f2bf(f0.w),
                f2bf(f1.x), f2bf(f1.y), f2bf(f1.z), f2bf(f1.w) };
    ((us8_t*)Wb)[i] = w;
  }
}

// =====================================================================
// Stage 1: h[n,o,v] = sum_c W[o,c]*x[n,v,c] + b[o]  (bf16 out, raw h)
// =====================================================================
__global__ __launch_bounds__(256) void k_gemm1(
    const unsigned short* __restrict__ Wb, const unsigned short* __restrict__ Xb,
    const float* __restrict__ convb, unsigned short* __restrict__ H) {
  __shared__ unsigned short As[128][32];
  __shared__ unsigned short Bs[128][32];
  const int tid = threadIdx.x;
  const int L = blockIdx.x;
  const int xcd = L & 7, slot = L >> 3;
  const int n = xcd * 8 + (slot >> 5);
  const int tile = slot & 31;
  const int tm = tile >> 2, tn = tile & 3;
  const unsigned short* gA = Wb + (size_t)tm * 128 * 512;
  const unsigned short* gB = Xb + ((size_t)n * 512 + tn * 128) * 512;
  const int lane = tid & 63, wid = tid >> 6;
  const int wr = (wid >> 1) * 64, wc = (wid & 1) * 64;
  const int lr = lane & 15, lk = lane >> 4;
  f32x4 acc[4][4] = {};
  for (int k0 = 0; k0 < 512; k0 += 32) {
    stage_tile(gA + k0, 512, &As[0][0], wid, lane);
    stage_tile(gB + k0, 512, &Bs[0][0], wid, lane);
    __syncthreads();
    bf16x8 a[4], b[4];
#pragma unroll
    for (int mi = 0; mi < 4; ++mi) a[mi] = *(const bf16x8*)&As[wr + mi * 16 + lr][lk * 8];
#pragma unroll
    for (int ni = 0; ni < 4; ++ni) b[ni] = *(const bf16x8*)&Bs[wc + ni * 16 + lr][lk * 8];
#pragma unroll
    for (int mi = 0; mi < 4; ++mi)
#pragma unroll
      for (int ni = 0; ni < 4; ++ni)
        acc[mi][ni] = __builtin_amdgcn_mfma_f32_16x16x32_bf16(a[mi], b[ni], acc[mi][ni], 0, 0, 0);
    __syncthreads();
  }
  unsigned short* Hn = H + (size_t)n * 1024 * 512;
#pragma unroll
  for (int mi = 0; mi < 4; ++mi)
#pragma unroll
    for (int i = 0; i < 4; ++i) {
      int o = tm * 128 + wr + mi * 16 + lk * 4 + i;
      float bias = convb[o];
#pragma unroll
      for (int ni = 0; ni < 4; ++ni) {
        int v = tn * 128 + wc + ni * 16 + lr;
        Hn[(size_t)o * 512 + v] = f2bf(acc[mi][ni][i] + bias);
      }
    }
}

// =====================================================================
// BN stats from raw H -> scale/shift
// =====================================================================
__global__ __launch_bounds__(256) void k_bn(
    const unsigned short* __restrict__ H, const float* __restrict__ gamma,
    const float* __restrict__ beta, float* __restrict__ sc_sh) {
  const int o = blockIdx.x;
  const int tid = threadIdx.x;
  const int g = tid >> 6, l = tid & 63;
  float s1 = 0.f, s2 = 0.f;
  for (int step = 0; step < 16; ++step) {
    int n = g + step * 4;
    const us8_t* row = (const us8_t*)(H + ((size_t)n * 1024 + o) * 512);
    us8_t v = row[l];
#pragma unroll
    for (int j = 0; j < 8; ++j) { float f = bf2f(v[j]); s1 += f; s2 += f * f; }
  }
  __shared__ float r1[256], r2[256];
  r1[tid] = s1; r2[tid] = s2;
  __syncthreads();
  for (int off = 128; off > 0; off >>= 1) {
    if (tid < off) { r1[tid] += r1[tid + off]; r2[tid] += r2[tid + off]; }
    __syncthreads();
  }
  if (tid == 0) {
    float mean = r1[0] * (1.0f / 32768.0f);
    float var = r2[0] * (1.0f / 32768.0f) - mean * mean;
    float s = gamma[o] * rsqrtf(var + 1e-5f);
    sc_sh[o] = s;
    sc_sh[1024 + o] = beta[o] - mean * s;
  }
}

// =====================================================================
// Fallback only (ws too small): in-place affine on H.
// =====================================================================
__global__ __launch_bounds__(256) void k_affine(
    unsigned short* __restrict__ H, const float* __restrict__ sc_sh) {
  const size_t idx = (size_t)blockIdx.x * 256 + threadIdx.x;
  const size_t stride = (size_t)gridDim.x * 256;
  const size_t total8 = (size_t)64 * 1024 * 512 / 8;
  for (size_t i = idx; i < total8; i += stride) {
    size_t base = i * 8;
    int o = (int)((base >> 9) & 1023);
    float sc = sc_sh[o], sh = sc_sh[1024 + o];
    us8_t v = ((const us8_t*)H)[i];
    us8_t w;
#pragma unroll
    for (int j = 0; j < 8; ++j) w[j] = f2bf(fmaf(bf2f(v[j]), sc, sh));
    ((us8_t*)H)[i] = w;
  }
}

// =====================================================================
// Stage 2': B2[nk][m,m'] = sum_e A[m,e]*A[m',e]  (fp32 in, reg-staged)
// SYMMETRIC: only tm<=tn tiles computed (10 of 16); mirror via LDS bounce.
// grid 1280 = 8 XCD x 16 nk x 10 tiles.
// =====================================================================
__global__ __launch_bounds__(256) void k_aat(
    const float* __restrict__ A, unsigned short* __restrict__ B2) {
  __shared__ unsigned short smem[2 * 128 * LDSK];  // As | Bs; reused for mirror
  unsigned short (*As)[LDSK] = (unsigned short(*)[LDSK])smem;
  unsigned short (*Bs)[LDSK] = (unsigned short(*)[LDSK])(smem + 128 * LDSK);
  const int tid = threadIdx.x;
  const int L = blockIdx.x;
  const int xcd = L & 7, slot = L >> 3;        // slot 0..159
  const int nk = xcd * 16 + slot / 10;
  const int t = slot % 10;
  const int tm = (t >= 4) + (t >= 7) + (t >= 9);
  const int base = (tm == 0) ? 0 : (tm == 1) ? 4 : (tm == 2) ? 7 : 9;
  const int tn = t - base + tm;
  const bool diag = (tm == tn);
  const float* Ank = A + (size_t)nk * 512 * 512;
  const float* gA = Ank + (size_t)tm * 128 * 512;
  const float* gB = Ank + (size_t)tn * 128 * 512;
  const int lane = tid & 63, wid = tid >> 6;
  const int wr = (wid >> 1) * 64, wc = (wid & 1) * 64;
  const int lr = lane & 15, lk = lane >> 4;
  f32x4 acc[4][4] = {};
  for (int k0 = 0; k0 < 512; k0 += 32) {
#pragma unroll
    for (int i = 0; i < 4; ++i) {
      int s = tid + i * 256;
      int r = s >> 3, c4 = (s & 7) * 4;
      float4 fa = *(const float4*)(gA + (size_t)r * 512 + k0 + c4);
      us4_t ua = { f2bf(fa.x), f2bf(fa.y), f2bf(fa.z), f2bf(fa.w) };
      *(us4_t*)&As[r][c4] = ua;
      if (!diag) {
        float4 fb = *(const float4*)(gB + (size_t)r * 512 + k0 + c4);
        us4_t ub = { f2bf(fb.x), f2bf(fb.y), f2bf(fb.z), f2bf(fb.w) };
        *(us4_t*)&Bs[r][c4] = ub;
      }
    }
    __syncthreads();
    bf16x8 a[4], b[4];
#pragma unroll
    for (int mi = 0; mi < 4; ++mi) a[mi] = *(const bf16x8*)&As[wr + mi * 16 + lr][lk * 8];
    if (diag) {
#pragma unroll
      for (int ni = 0; ni < 4; ++ni) b[ni] = *(const bf16x8*)&As[wc + ni * 16 + lr][lk * 8];
    } else {
#pragma unroll
      for (int ni = 0; ni < 4; ++ni) b[ni] = *(const bf16x8*)&Bs[wc + ni * 16 + lr][lk * 8];
    }
#pragma unroll
    for (int mi = 0; mi < 4; ++mi)
#pragma unroll
      for (int ni = 0; ni < 4; ++ni)
        acc[mi][ni] = __builtin_amdgcn_mfma_f32_16x16x32_bf16(a[mi], b[ni], acc[mi][ni], 0, 0, 0);
    __syncthreads();
  }
  unsigned short* Bn = B2 + (size_t)nk * 512 * 512;
  // direct tile (tm, tn)
#pragma unroll
  for (int mi = 0; mi < 4; ++mi)
#pragma unroll
    for (int i = 0; i < 4; ++i) {
      int m = tm * 128 + wr + mi * 16 + lk * 4 + i;
#pragma unroll
      for (int ni = 0; ni < 4; ++ni) {
        int mp = tn * 128 + wc + ni * 16 + lr;
        Bn[(size_t)m * 512 + mp] = f2bf(acc[mi][ni][i]);
      }
    }
  // mirror tile (tn, tm) via LDS bounce, two 64x128 halves
  if (!diag) {
    unsigned short (*Tl)[136] = (unsigned short(*)[136])smem;  // 64*136*2 = 17.4KB <= 20.5KB
#pragma unroll
    for (int h = 0; h < 2; ++h) {
      __syncthreads();
      if ((wid & 1) == h) {  // these waves own cols [h*64, h*64+64)
#pragma unroll
        for (int ni = 0; ni < 4; ++ni)
#pragma unroll
          for (int mi = 0; mi < 4; ++mi)
#pragma unroll
            for (int i = 0; i < 4; i += 2) {
              int rloc = ni * 16 + lr;               // 0..63
              int cloc = wr + mi * 16 + lk * 4 + i;  // 0..127, even
              uint32_t pair = (uint32_t)f2bf(acc[mi][ni][i]) |
                              ((uint32_t)f2bf(acc[mi][ni][i + 1]) << 16);
              *(uint32_t*)&Tl[rloc][cloc] = pair;
            }
      }
      __syncthreads();
#pragma unroll
      for (int j = 0; j < 4; ++j) {
        int ch = tid + j * 256;  // 0..1023
        int r = ch >> 4, c8 = (ch & 15) * 8;
        us8_t v = *(const us8_t*)&Tl[r][c8];
        *(us8_t*)&Bn[(size_t)(tn * 128 + h * 64 + r) * 512 + tm * 128 + c8] = v;
      }
    }
  }
}

// =====================================================================
// Stage 3': out[n,v,c] = (1+eps)*x + sum_kk sum_m' B2[nk][v,m'] * h'[o,m']
// =====================================================================
template <bool AFFINE>
__global__ __launch_bounds__(256) void k_gemm3(
    const unsigned short* __restrict__ B2, const unsigned short* __restrict__ H,
    const float* __restrict__ sc_sh, const float* __restrict__ X,
    const float* __restrict__ epsp, float* __restrict__ out) {
  __shared__ unsigned short As[128][32];    // linear: global_load_lds dest
  __shared__ unsigned short Bs[128][LDSK];  // padded: reg-staged
  __shared__ float s_sc[2][128], s_sh[2][128];
  const int tid = threadIdx.x;
  const int L = blockIdx.x;
  const int xcd = L & 7, slot = L >> 3;
  const int n = xcd * 8 + (slot >> 4);
  const int tile = slot & 15;
  const int tm = tile >> 2, tn = tile & 3;
  const int lane = tid & 63, wid = tid >> 6;
  const int wr = (wid >> 1) * 64, wc = (wid & 1) * 64;
  const int lr = lane & 15, lk = lane >> 4;
  if (AFFINE) {
    if (tid < 256) {
      int kkq = tid >> 7, r = tid & 127;
      s_sc[kkq][r] = sc_sh[kkq * 512 + tn * 128 + r];
      s_sh[kkq][r] = sc_sh[1024 + kkq * 512 + tn * 128 + r];
    }
    __syncthreads();
  }
  f32x4 acc[4][4] = {};
  for (int kk = 0; kk < 2; ++kk) {
    const unsigned short* gA = B2 + ((size_t)(n * 2 + kk) * 512 + tm * 128) * 512;
    const unsigned short* gB = H + ((size_t)n * 1024 + kk * 512 + tn * 128) * 512;
    for (int k0 = 0; k0 < 512; k0 += 32) {
      stage_tile(gA + k0, 512, &As[0][0], wid, lane);  // async, overlaps Bs staging
#pragma unroll
      for (int i = 0; i < 2; ++i) {
        int s = tid + i * 256;
        int r = s >> 2, c8 = (s & 3) * 8;
        us8_t v = *(const us8_t*)(gB + (size_t)r * 512 + k0 + c8);
        if (AFFINE) {
          float sc = s_sc[kk][r], sh = s_sh[kk][r];
          us8_t w;
#pragma unroll
          for (int j = 0; j < 8; ++j) w[j] = f2bf(fmaf(bf2f(v[j]), sc, sh));
          *(us8_t*)&Bs[r][c8] = w;
        } else {
          *(us8_t*)&Bs[r][c8] = v;
        }
      }
      __syncthreads();
      bf16x8 a[4], b[4];
#pragma unroll
      for (int mi = 0; mi < 4; ++mi) a[mi] = *(const bf16x8*)&As[wr + mi * 16 + lr][lk * 8];
#pragma unroll
      for (int ni = 0; ni < 4; ++ni) b[ni] = *(const bf16x8*)&Bs[wc + ni * 16 + lr][lk * 8];
#pragma unroll
      for (int mi = 0; mi < 4; ++mi)
#pragma unroll
        for (int ni = 0; ni < 4; ++ni)
          acc[mi][ni] = __builtin_amdgcn_mfma_f32_16x16x32_bf16(a[mi], b[ni], acc[mi][ni], 0, 0, 0);
      __syncthreads();
    }
  }
  const float e1 = 1.0f + epsp[0];
#pragma unroll
  for (int mi = 0; mi < 4; ++mi)
#pragma unroll
    for (int i = 0; i < 4; ++i) {
      int v = tm * 128 + wr + mi * 16 + lk * 4 + i;
#pragma unroll
      for (int ni = 0; ni < 4; ++ni) {
        int c = tn * 128 + wc + ni * 16 + lr;
        size_t idx = ((size_t)n * 512 + v) * 512 + c;
        out[idx] = fmaf(e1, X[idx], acc[mi][ni][i]);
      }
    }
}

// =====================================================================
// At[nk,e,m] = A[nk,m,e]  (runs LAST) — 64x64 float4 tiles
// =====================================================================
__global__ __launch_bounds__(256) void k_at(
    const float* __restrict__ A, float* __restrict__ At) {
  __shared__ float tile[64][65];
  const int nk = blockIdx.z;
  const int e0 = blockIdx.x * 64, m0 = blockIdx.y * 64;
  const float* src = A + (size_t)nk * 262144;
  float* dst = At + (size_t)nk * 262144;
  const int t = threadIdx.x;
#pragma unroll
  for (int j = 0; j < 4; ++j) {
    int ch = t + j * 256;
    int r = ch >> 4, c4 = (ch & 15) * 4;
    float4 f = *(const float4*)(src + (size_t)(m0 + r) * 512 + e0 + c4);
    tile[r][c4] = f.x; tile[r][c4 + 1] = f.y; tile[r][c4 + 2] = f.z; tile[r][c4 + 3] = f.w;
  }
  __syncthreads();
#pragma unroll
  for (int j = 0; j < 4; ++j) {
    int ch = t + j * 256;
    int e = ch >> 4, m4 = (ch & 15) * 4;
    float4 g = { tile[m4][e], tile[m4 + 1][e], tile[m4 + 2][e], tile[m4 + 3][e] };
    *(float4*)(dst + (size_t)(e0 + e) * 512 + m0 + m4) = g;
  }
}

// =====================================================================
extern "C" void kernel_launch(void* const* d_in, const int* in_sizes, int n_in,
                              void* d_out, int out_size, void* d_ws, size_t ws_size,
                              hipStream_t stream) {
  const float* x      = (const float*)d_in[0];  // (64,512,512)
  const float* A      = (const float*)d_in[1];  // (64,2,512,512)
  const float* conv_w = (const float*)d_in[2];  // (1024,512)
  const float* conv_b = (const float*)d_in[3];  // (1024,)
  const float* gamma  = (const float*)d_in[4];  // (1024,)
  const float* beta   = (const float*)d_in[5];  // (1024,)
  const float* eps_p  = (const float*)d_in[6];  // (1,)

  float* out = (float*)d_out;           // 16,777,216 floats
  float* At  = out + (size_t)16777216;  // 33,554,432 floats

  // Scratch (all inside d_out, every byte dead before its final write):
  //   At region: B2 bf16 [0..33.5M shorts) | H bf16 [33.5M..67M shorts)
  //   out region: x_bf16 [0..16.7M shorts) | W_bf16 [16.7M..17.3M shorts)
  unsigned short* B2 = (unsigned short*)At;
  unsigned short* H  = (unsigned short*)(At + (size_t)16777216);
  unsigned short* Xb = (unsigned short*)out;
  unsigned short* Wb = Xb + (size_t)16777216;

  const bool use_ws = (ws_size >= 8192);
  float* sc_sh = use_ws ? (float*)d_ws : out;

  k_convert<<<2048, 256, 0, stream>>>(x, conv_w, Xb, Wb);
  k_gemm1  <<<2048, 256, 0, stream>>>(Wb, Xb, conv_b, H);
  k_bn     <<<1024, 256, 0, stream>>>(H, gamma, beta, sc_sh);
  k_aat    <<<1280, 256, 0, stream>>>(A, B2);
  if (use_ws) {
    k_gemm3<true><<<1024, 256, 0, stream>>>(B2, H, sc_sh, x, eps_p, out);
  } else {
    k_affine<<<2048, 256, 0, stream>>>(H, sc_sh);
    k_gemm3<false><<<1024, 256, 0, stream>>>(B2, H, nullptr, x, eps_p, out);
  }
  k_at<<<dim3(8, 8, 128), 256, 0, stream>>>(A, At);
}

// Round 5
// 294.044 us; speedup vs baseline: 1.1167x; 1.1167x over previous
//
#include <hip/hip_runtime.h>
#include <stdint.h>

// ---------- types ----------
typedef __bf16 bf16x8 __attribute__((ext_vector_type(8)));
typedef float f32x4 __attribute__((ext_vector_type(4)));
typedef unsigned short us4_t __attribute__((ext_vector_type(4)));
typedef unsigned short us8_t __attribute__((ext_vector_type(8)));

#define LDSK 40  // padded row (reg-staged tiles): 32 bf16 + 8 pad

__device__ __forceinline__ unsigned short f2bf(float f) {
  __bf16 b = (__bf16)f;
  return __builtin_bit_cast(unsigned short, b);
}
__device__ __forceinline__ float bf2f(unsigned short u) {
  union { uint32_t u; float f; } v; v.u = ((uint32_t)u) << 16;
  return v.f;
}

// async global->LDS, 16B per lane (wave-uniform LDS base + lane*16)
__device__ __forceinline__ void gload16(const void* g, void* l) {
  __builtin_amdgcn_global_load_lds(
      (const __attribute__((address_space(1))) void*)g,
      (__attribute__((address_space(3))) void*)l, 16, 0, 0);
}

// Stage a 128x32-short bf16 tile (linear [128][32] LDS) via 2 gload16/wave.
__device__ __forceinline__ void stage_tile(const unsigned short* g, size_t ldg,
                                           unsigned short* lds, int wid, int lane) {
#pragma unroll
  for (int i = 0; i < 2; ++i) {
    int seg = wid * 2 + i;  // 0..7, 16 rows each
    const unsigned short* gp = g + (size_t)(seg * 16 + (lane >> 2)) * ldg + (lane & 3) * 8;
    gload16(gp, lds + seg * 512);
  }
}

// Stage a 128x32-float fp32 tile into LDS with granule swizzle:
// LDS granule (r, gl) holds source granule (r, gl ^ (r&7)).  (16B granules)
__device__ __forceinline__ void stage_tile_f32(const float* g, size_t ldg,
                                               float* lds, int wid, int lane) {
#pragma unroll
  for (int i = 0; i < 4; ++i) {
    int seg = wid * 4 + i;          // 0..15, 8 rows each
    int r = seg * 8 + (lane >> 3);  // row 0..127
    int gsw = (lane & 7) ^ (r & 7); // swizzled source granule
    const float* gp = g + (size_t)r * ldg + gsw * 4;
    gload16(gp, lds + seg * 256);   // wave-uniform base; lane*16B implicit
  }
}

// Read a bf16x8 MFMA fragment from a swizzled fp32 LDS tile (cvt on read).
__device__ __forceinline__ bf16x8 fragf(const float* lds, int row, int lk) {
  const float* rp = lds + row * 32;
  const int m = row & 7;
  f32x4 q0 = *(const f32x4*)(rp + ((((lk * 2) ^ m)) << 2));
  f32x4 q1 = *(const f32x4*)(rp + ((((lk * 2 + 1) ^ m)) << 2));
  bf16x8 r;
  r[0] = (__bf16)q0[0]; r[1] = (__bf16)q0[1]; r[2] = (__bf16)q0[2]; r[3] = (__bf16)q0[3];
  r[4] = (__bf16)q1[0]; r[5] = (__bf16)q1[1]; r[6] = (__bf16)q1[2]; r[7] = (__bf16)q1[3];
  return r;
}

// =====================================================================
// Convert x (16.7M f32) and W (0.52M f32) to bf16 (into out region).
// =====================================================================
__global__ __launch_bounds__(256) void k_convert(
    const float* __restrict__ X, const float* __restrict__ W,
    unsigned short* __restrict__ Xb, unsigned short* __restrict__ Wb) {
  const size_t idx = (size_t)blockIdx.x * 256 + threadIdx.x;
  const size_t stride = (size_t)gridDim.x * 256;
  for (size_t i = idx; i < (size_t)16777216 / 8; i += stride) {
    float4 f0 = ((const float4*)X)[2 * i], f1 = ((const float4*)X)[2 * i + 1];
    us8_t w = { f2bf(f0.x), f2bf(f0.y), f2bf(f0.z), f2bf(f0.w),
                f2bf(f1.x), f2bf(f1.y), f2bf(f1.z), f2bf(f1.w) };
    ((us8_t*)Xb)[i] = w;
  }
  for (size_t i = idx; i < (size_t)524288 / 8; i += stride) {
    float4 f0 = ((const float4*)W)[2 * i], f1 = ((const float4*)W)[2 * i + 1];
    us8_t w = { f2bf(f0.x), f2bf(f0.y), f2bf(f0.z), f2bf(f0.w),
                f2bf(f1.x), f2bf(f1.y), f2bf(f1.z), f2bf(f1.w) };
    ((us8_t*)Wb)[i] = w;
  }
}

// =====================================================================
// Stage 1: h[n,o,v] = sum_c W[o,c]*x[n,v,c] + b[o]  (bf16 out, raw h)
// =====================================================================
__global__ __launch_bounds__(256) void k_gemm1(
    const unsigned short* __restrict__ Wb, const unsigned short* __restrict__ Xb,
    const float* __restrict__ convb, unsigned short* __restrict__ H) {
  __shared__ unsigned short As[128][32];
  __shared__ unsigned short Bs[128][32];
  const int tid = threadIdx.x;
  const int L = blockIdx.x;
  const int xcd = L & 7, slot = L >> 3;
  const int n = xcd * 8 + (slot >> 5);
  const int tile = slot & 31;
  const int tm = tile >> 2, tn = tile & 3;
  const unsigned short* gA = Wb + (size_t)tm * 128 * 512;
  const unsigned short* gB = Xb + ((size_t)n * 512 + tn * 128) * 512;
  const int lane = tid & 63, wid = tid >> 6;
  const int wr = (wid >> 1) * 64, wc = (wid & 1) * 64;
  const int lr = lane & 15, lk = lane >> 4;
  f32x4 acc[4][4] = {};
  for (int k0 = 0; k0 < 512; k0 += 32) {
    stage_tile(gA + k0, 512, &As[0][0], wid, lane);
    stage_tile(gB + k0, 512, &Bs[0][0], wid, lane);
    __syncthreads();
    bf16x8 a[4], b[4];
#pragma unroll
    for (int mi = 0; mi < 4; ++mi) a[mi] = *(const bf16x8*)&As[wr + mi * 16 + lr][lk * 8];
#pragma unroll
    for (int ni = 0; ni < 4; ++ni) b[ni] = *(const bf16x8*)&Bs[wc + ni * 16 + lr][lk * 8];
#pragma unroll
    for (int mi = 0; mi < 4; ++mi)
#pragma unroll
      for (int ni = 0; ni < 4; ++ni)
        acc[mi][ni] = __builtin_amdgcn_mfma_f32_16x16x32_bf16(a[mi], b[ni], acc[mi][ni], 0, 0, 0);
    __syncthreads();
  }
  unsigned short* Hn = H + (size_t)n * 1024 * 512;
#pragma unroll
  for (int mi = 0; mi < 4; ++mi)
#pragma unroll
    for (int i = 0; i < 4; ++i) {
      int o = tm * 128 + wr + mi * 16 + lk * 4 + i;
      float bias = convb[o];
#pragma unroll
      for (int ni = 0; ni < 4; ++ni) {
        int v = tn * 128 + wc + ni * 16 + lr;
        Hn[(size_t)o * 512 + v] = f2bf(acc[mi][ni][i] + bias);
      }
    }
}

// =====================================================================
// BN stats from raw H -> scale/shift
// =====================================================================
__global__ __launch_bounds__(256) void k_bn(
    const unsigned short* __restrict__ H, const float* __restrict__ gamma,
    const float* __restrict__ beta, float* __restrict__ sc_sh) {
  const int o = blockIdx.x;
  const int tid = threadIdx.x;
  const int g = tid >> 6, l = tid & 63;
  float s1 = 0.f, s2 = 0.f;
  for (int step = 0; step < 16; ++step) {
    int n = g + step * 4;
    const us8_t* row = (const us8_t*)(H + ((size_t)n * 1024 + o) * 512);
    us8_t v = row[l];
#pragma unroll
    for (int j = 0; j < 8; ++j) { float f = bf2f(v[j]); s1 += f; s2 += f * f; }
  }
  __shared__ float r1[256], r2[256];
  r1[tid] = s1; r2[tid] = s2;
  __syncthreads();
  for (int off = 128; off > 0; off >>= 1) {
    if (tid < off) { r1[tid] += r1[tid + off]; r2[tid] += r2[tid + off]; }
    __syncthreads();
  }
  if (tid == 0) {
    float mean = r1[0] * (1.0f / 32768.0f);
    float var = r2[0] * (1.0f / 32768.0f) - mean * mean;
    float s = gamma[o] * rsqrtf(var + 1e-5f);
    sc_sh[o] = s;
    sc_sh[1024 + o] = beta[o] - mean * s;
  }
}

// =====================================================================
// Fallback only (ws too small): in-place affine on H.
// =====================================================================
__global__ __launch_bounds__(256) void k_affine(
    unsigned short* __restrict__ H, const float* __restrict__ sc_sh) {
  const size_t idx = (size_t)blockIdx.x * 256 + threadIdx.x;
  const size_t stride = (size_t)gridDim.x * 256;
  const size_t total8 = (size_t)64 * 1024 * 512 / 8;
  for (size_t i = idx; i < total8; i += stride) {
    size_t base = i * 8;
    int o = (int)((base >> 9) & 1023);
    float sc = sc_sh[o], sh = sc_sh[1024 + o];
    us8_t v = ((const us8_t*)H)[i];
    us8_t w;
#pragma unroll
    for (int j = 0; j < 8; ++j) w[j] = f2bf(fmaf(bf2f(v[j]), sc, sh));
    ((us8_t*)H)[i] = w;
  }
}

// =====================================================================
// Stage 2': B2[nk][m,m'] = sum_e A[m,e]*A[m',e]
// fp32 operands staged via global_load_lds (swizzled granules),
// bf16 conversion on fragment read. grid 2048 (16 tiles x 128 nk).
// =====================================================================
__global__ __launch_bounds__(256) void k_aat(
    const float* __restrict__ A, unsigned short* __restrict__ B2) {
  __shared__ __align__(16) float Afs[128 * 32];
  __shared__ __align__(16) float Bfs[128 * 32];
  const int tid = threadIdx.x;
  const int L = blockIdx.x;
  const int xcd = L & 7, slot = L >> 3;
  const int nk = xcd * 16 + (slot >> 4);
  const int tile = slot & 15;
  const int tm = tile >> 2, tn = tile & 3;
  const float* Ank = A + (size_t)nk * 262144;
  const float* gA = Ank + (size_t)tm * 128 * 512;
  const float* gB = Ank + (size_t)tn * 128 * 512;
  const int lane = tid & 63, wid = tid >> 6;
  const int wr = (wid >> 1) * 64, wc = (wid & 1) * 64;
  const int lr = lane & 15, lk = lane >> 4;
  f32x4 acc[4][4] = {};
  for (int k0 = 0; k0 < 512; k0 += 32) {
    stage_tile_f32(gA + k0, 512, Afs, wid, lane);
    stage_tile_f32(gB + k0, 512, Bfs, wid, lane);
    __syncthreads();
    bf16x8 a[4], b[4];
#pragma unroll
    for (int mi = 0; mi < 4; ++mi) a[mi] = fragf(Afs, wr + mi * 16 + lr, lk);
#pragma unroll
    for (int ni = 0; ni < 4; ++ni) b[ni] = fragf(Bfs, wc + ni * 16 + lr, lk);
#pragma unroll
    for (int mi = 0; mi < 4; ++mi)
#pragma unroll
      for (int ni = 0; ni < 4; ++ni)
        acc[mi][ni] = __builtin_amdgcn_mfma_f32_16x16x32_bf16(a[mi], b[ni], acc[mi][ni], 0, 0, 0);
    __syncthreads();
  }
  unsigned short* Bn = B2 + (size_t)nk * 262144;
#pragma unroll
  for (int mi = 0; mi < 4; ++mi)
#pragma unroll
    for (int i = 0; i < 4; ++i) {
      int m = tm * 128 + wr + mi * 16 + lk * 4 + i;
#pragma unroll
      for (int ni = 0; ni < 4; ++ni) {
        int mp = tn * 128 + wc + ni * 16 + lr;
        Bn[(size_t)m * 512 + mp] = f2bf(acc[mi][ni][i]);
      }
    }
}

// =====================================================================
// Stage 3': out[n,v,c] = (1+eps)*x + sum_kk sum_m' B2[nk][v,m'] * h'[o,m']
// =====================================================================
template <bool AFFINE>
__global__ __launch_bounds__(256) void k_gemm3(
    const unsigned short* __restrict__ B2, const unsigned short* __restrict__ H,
    const float* __restrict__ sc_sh, const float* __restrict__ X,
    const float* __restrict__ epsp, float* __restrict__ out) {
  __shared__ unsigned short As[128][32];    // linear: global_load_lds dest
  __shared__ unsigned short Bs[128][LDSK];  // padded: reg-staged
  __shared__ float s_sc[2][128], s_sh[2][128];
  const int tid = threadIdx.x;
  const int L = blockIdx.x;
  const int xcd = L & 7, slot = L >> 3;
  const int n = xcd * 8 + (slot >> 4);
  const int tile = slot & 15;
  const int tm = tile >> 2, tn = tile & 3;
  const int lane = tid & 63, wid = tid >> 6;
  const int wr = (wid >> 1) * 64, wc = (wid & 1) * 64;
  const int lr = lane & 15, lk = lane >> 4;
  if (AFFINE) {
    if (tid < 256) {
      int kkq = tid >> 7, r = tid & 127;
      s_sc[kkq][r] = sc_sh[kkq * 512 + tn * 128 + r];
      s_sh[kkq][r] = sc_sh[1024 + kkq * 512 + tn * 128 + r];
    }
    __syncthreads();
  }
  f32x4 acc[4][4] = {};
  for (int kk = 0; kk < 2; ++kk) {
    const unsigned short* gA = B2 + ((size_t)(n * 2 + kk) * 512 + tm * 128) * 512;
    const unsigned short* gB = H + ((size_t)n * 1024 + kk * 512 + tn * 128) * 512;
    for (int k0 = 0; k0 < 512; k0 += 32) {
      stage_tile(gA + k0, 512, &As[0][0], wid, lane);  // async, overlaps Bs staging
#pragma unroll
      for (int i = 0; i < 2; ++i) {
        int s = tid + i * 256;
        int r = s >> 2, c8 = (s & 3) * 8;
        us8_t v = *(const us8_t*)(gB + (size_t)r * 512 + k0 + c8);
        if (AFFINE) {
          float sc = s_sc[kk][r], sh = s_sh[kk][r];
          us8_t w;
#pragma unroll
          for (int j = 0; j < 8; ++j) w[j] = f2bf(fmaf(bf2f(v[j]), sc, sh));
          *(us8_t*)&Bs[r][c8] = w;
        } else {
          *(us8_t*)&Bs[r][c8] = v;
        }
      }
      __syncthreads();
      bf16x8 a[4], b[4];
#pragma unroll
      for (int mi = 0; mi < 4; ++mi) a[mi] = *(const bf16x8*)&As[wr + mi * 16 + lr][lk * 8];
#pragma unroll
      for (int ni = 0; ni < 4; ++ni) b[ni] = *(const bf16x8*)&Bs[wc + ni * 16 + lr][lk * 8];
#pragma unroll
      for (int mi = 0; mi < 4; ++mi)
#pragma unroll
        for (int ni = 0; ni < 4; ++ni)
          acc[mi][ni] = __builtin_amdgcn_mfma_f32_16x16x32_bf16(a[mi], b[ni], acc[mi][ni], 0, 0, 0);
      __syncthreads();
    }
  }
  const float e1 = 1.0f + epsp[0];
#pragma unroll
  for (int mi = 0; mi < 4; ++mi)
#pragma unroll
    for (int i = 0; i < 4; ++i) {
      int v = tm * 128 + wr + mi * 16 + lk * 4 + i;
#pragma unroll
      for (int ni = 0; ni < 4; ++ni) {
        int c = tn * 128 + wc + ni * 16 + lr;
        size_t idx = ((size_t)n * 512 + v) * 512 + c;
        out[idx] = fmaf(e1, X[idx], acc[mi][ni][i]);
      }
    }
}

// =====================================================================
// At[nk,e,m] = A[nk,m,e]  (runs LAST) — 64x64 float4 tiles
// =====================================================================
__global__ __launch_bounds__(256) void k_at(
    const float* __restrict__ A, float* __restrict__ At) {
  __shared__ float tile[64][65];
  const int nk = blockIdx.z;
  const int e0 = blockIdx.x * 64, m0 = blockIdx.y * 64;
  const float* src = A + (size_t)nk * 262144;
  float* dst = At + (size_t)nk * 262144;
  const int t = threadIdx.x;
#pragma unroll
  for (int j = 0; j < 4; ++j) {
    int ch = t + j * 256;
    int r = ch >> 4, c4 = (ch & 15) * 4;
    float4 f = *(const float4*)(src + (size_t)(m0 + r) * 512 + e0 + c4);
    tile[r][c4] = f.x; tile[r][c4 + 1] = f.y; tile[r][c4 + 2] = f.z; tile[r][c4 + 3] = f.w;
  }
  __syncthreads();
#pragma unroll
  for (int j = 0; j < 4; ++j) {
    int ch = t + j * 256;
    int e = ch >> 4, m4 = (ch & 15) * 4;
    float4 g = { tile[m4][e], tile[m4 + 1][e], tile[m4 + 2][e], tile[m4 + 3][e] };
    *(float4*)(dst + (size_t)(e0 + e) * 512 + m0 + m4) = g;
  }
}

// =====================================================================
extern "C" void kernel_launch(void* const* d_in, const int* in_sizes, int n_in,
                              void* d_out, int out_size, void* d_ws, size_t ws_size,
                              hipStream_t stream) {
  const float* x      = (const float*)d_in[0];  // (64,512,512)
  const float* A      = (const float*)d_in[1];  // (64,2,512,512)
  const float* conv_w = (const float*)d_in[2];  // (1024,512)
  const float* conv_b = (const float*)d_in[3];  // (1024,)
  const float* gamma  = (const float*)d_in[4];  // (1024,)
  const float* beta   = (const float*)d_in[5];  // (1024,)
  const float* eps_p  = (const float*)d_in[6];  // (1,)

  float* out = (float*)d_out;           // 16,777,216 floats
  float* At  = out + (size_t)16777216;  // 33,554,432 floats

  // Scratch (all inside d_out, every byte dead before its final write):
  //   At region: B2 bf16 [0..33.5M shorts) | H bf16 [33.5M..67M shorts)
  //   out region: x_bf16 [0..16.7M shorts) | W_bf16 [16.7M..17.3M shorts)
  unsigned short* B2 = (unsigned short*)At;
  unsigned short* H  = (unsigned short*)(At + (size_t)16777216);
  unsigned short* Xb = (unsigned short*)out;
  unsigned short* Wb = Xb + (size_t)16777216;

  const bool use_ws = (ws_size >= 8192);
  float* sc_sh = use_ws ? (float*)d_ws : out;

  k_convert<<<2048, 256, 0, stream>>>(x, conv_w, Xb, Wb);
  k_gemm1  <<<2048, 256, 0, stream>>>(Wb, Xb, conv_b, H);
  k_bn     <<<1024, 256, 0, stream>>>(H, gamma, beta, sc_sh);
  k_aat    <<<2048, 256, 0, stream>>>(A, B2);
  if (use_ws) {
    k_gemm3<true><<<1024, 256, 0, stream>>>(B2, H, sc_sh, x, eps_p, out);
  } else {
    k_affine<<<2048, 256, 0, stream>>>(H, sc_sh);
    k_gemm3<false><<<1024, 256, 0, stream>>>(B2, H, nullptr, x, eps_p, out);
  }
  k_at<<<dim3(8, 8, 128), 256, 0, stream>>>(A, At);
}